// Round 1
// baseline (286.589 us; speedup 1.0000x reference)
//
#include <hip/hip_runtime.h>

#define LN_EPS 1e-5f
#define D 128
#define SCAN_CHUNK 1024
#define LDSA_STRIDE 264   // bf16 units: 256 + 8 pad; row stride 528B (16B-aligned)

typedef __attribute__((ext_vector_type(4))) float f32x4;
typedef __attribute__((ext_vector_type(8))) short bf16x8;

static __device__ __forceinline__ ushort f2bf(float f) {
    union { float f; unsigned u; } a; a.f = f;
    unsigned r = a.u + 0x7FFF + ((a.u >> 16) & 1);   // RNE
    return (ushort)(r >> 16);
}
static __device__ __forceinline__ float bf2f(ushort u) {
    union { unsigned u; float f; } a; a.u = ((unsigned)u) << 16;
    return a.f;
}

// K0: pack B = [Wl^T ; Wr^T] (256k x 128j) into MFMA B-fragment order, and
// zero the degree histogram (folds the hipMemsetAsync dispatch in here).
__global__ void prep_w(const float* __restrict__ Wl,
                       const float* __restrict__ Wr,
                       ushort* __restrict__ Bfrag,
                       int* __restrict__ hist, int N) {
    int t = blockIdx.x * blockDim.x + threadIdx.x;
    if (t < 8 * 8 * 64 * 8) {
        int i    = t & 7;
        int lane = (t >> 3) & 63;
        int jb   = (t >> 9) & 7;
        int ks   = t >> 12;
        int k = ks * 32 + (lane >> 4) * 8 + i;
        int j = jb * 16 + (lane & 15);
        float v = (k < D) ? Wl[j * D + k] : Wr[j * D + (k - D)];
        Bfrag[t] = f2bf(v);
    }
    for (int i = t; i < N; i += gridDim.x * blockDim.x) hist[i] = 0;
}

// K1 (merged): blocks [0, histBlocks) do the dst-degree histogram (first, so
// the atomics overlap the LN bulk); blocks [histBlocks, ...) do
// LayerNorm+ReLU+mask -> bf16 h. LN: 2 nodes per 64-lane wave, float4 loads
// (16B/lane), 5-step half-wave shuffle reduction.
__global__ void ln_hist(const float* __restrict__ x,
                        const float* __restrict__ mask,
                        const float* __restrict__ gamma,
                        const float* __restrict__ beta,
                        ushort* __restrict__ hbf,
                        const int* __restrict__ ei,
                        int* __restrict__ hist,
                        int N, int E, int histBlocks) {
    if ((int)blockIdx.x < histBlocks) {
        int e = blockIdx.x * blockDim.x + threadIdx.x;
        if (e < E) atomicAdd(&hist[ei[E + e]], 1);
        return;
    }
    int lane = threadIdx.x & 63;
    int wid  = (((int)blockIdx.x - histBlocks) * (int)blockDim.x + (int)threadIdx.x) >> 6;
    int node = wid * 2 + (lane >> 5);      // lanes 0-31: node0, lanes 32-63: node1
    if (node >= N) return;
    int sl = lane & 31;                    // 32 lanes x float4 = 128 elems
    f32x4 v = ((const f32x4*)(x + (size_t)node * D))[sl];
    float s  = v.x + v.y + v.z + v.w;
    float ss = v.x * v.x + v.y * v.y + v.z * v.z + v.w * v.w;
#pragma unroll
    for (int off = 16; off > 0; off >>= 1) {   // xor<32 stays within each half
        s  += __shfl_xor(s, off);
        ss += __shfl_xor(ss, off);
    }
    float mu  = s * (1.0f / D);
    float var = ss * (1.0f / D) - mu * mu;
    float rs  = rsqrtf(var + LN_EPS);
    f32x4 g = ((const f32x4*)gamma)[sl];
    f32x4 b = ((const f32x4*)beta)[sl];
    f32x4 m = ((const f32x4*)(mask + (size_t)node * D))[sl];
    ushort4 o;
    o.x = f2bf(fmaxf((v.x - mu) * rs * g.x + b.x, 0.0f) * m.x);
    o.y = f2bf(fmaxf((v.y - mu) * rs * g.y + b.y, 0.0f) * m.y);
    o.z = f2bf(fmaxf((v.z - mu) * rs * g.z + b.z, 0.0f) * m.z);
    o.w = f2bf(fmaxf((v.w - mu) * rs * g.w + b.w, 0.0f) * m.w);
    ((ushort4*)(hbf + (size_t)node * D))[sl] = o;
}

// K2a: per-chunk exclusive scan (1024 elems / block); csums[b] = chunk total.
__global__ void scan1(const int* __restrict__ hist, int* __restrict__ offs,
                      int* __restrict__ chunk_sums, int N) {
    __shared__ int lds[256];
    int base = blockIdx.x * SCAN_CHUNK;
    int t = threadIdx.x;
    int idx0 = base + t * 4;
    int v[4];
#pragma unroll
    for (int i = 0; i < 4; i++) {
        int idx = idx0 + i;
        v[i] = (idx < N) ? hist[idx] : 0;
    }
    lds[t] = v[0] + v[1] + v[2] + v[3];
    __syncthreads();
    for (int off = 1; off < 256; off <<= 1) {
        int add = (t >= off) ? lds[t - off] : 0;
        __syncthreads();
        lds[t] += add;
        __syncthreads();
    }
    int run = (t == 0) ? 0 : lds[t - 1];
    if (t == 255) chunk_sums[blockIdx.x] = lds[255];
#pragma unroll
    for (int i = 0; i < 4; i++) {
        int idx = idx0 + i;
        if (idx < N) offs[idx] = run;
        run += v[i];
    }
}

// K2b: add chunk base and init the scatter cursor.
__global__ void scan_fix(int* __restrict__ offs, const int* __restrict__ csums,
                         int* __restrict__ cursor, int N) {
    __shared__ int base_s;
    int chunk = (blockIdx.x * 256) / SCAN_CHUNK;
    int t = threadIdx.x;
    if (t < 64) {
        int v = 0;
        for (int c = t; c < chunk; c += 64) v += csums[c];
#pragma unroll
        for (int off = 32; off > 0; off >>= 1) v += __shfl_xor(v, off);
        if (t == 0) base_s = v;
    }
    __syncthreads();
    int i = blockIdx.x * 256 + t;
    if (i >= N) return;
    int v = offs[i] + base_s;
    offs[i] = v;
    cursor[i] = v;
}

// K3: bucket edges by dst (counting-sort placement; int atomics only).
__global__ void sort_edges(const int* __restrict__ ei, int* __restrict__ cursor,
                           int* __restrict__ sorted_src, int E) {
    int e = blockIdx.x * blockDim.x + threadIdx.x;
    if (e >= E) return;
    int dst = ei[E + e];
    int pos = atomicAdd(&cursor[dst], 1);
    sorted_src[pos] = ei[e];
}

// K4 (fused): per block of 64 nodes: (A1) stage h rows into the A-tile,
// (A2) mean-aggregate the 64 rows directly into the A-tile (each 16-lane
// subgroup walks its 4 rows CONCURRENTLY -> 4 independent 256B gathers in
// flight per subgroup), then (B) [magg | h] @ B + bias via bf16 MFMA.
// Deletes the magg global round-trip (51 MB) and one kernel launch.
__global__ void __launch_bounds__(256, 3)
agg_gemm(float* __restrict__ out,
         const ushort* __restrict__ hbf,
         const int* __restrict__ sorted_src,
         const int* __restrict__ offs,
         const int* __restrict__ hist,
         const ushort* __restrict__ Bfrag,
         const float* __restrict__ bl,
         int N) {
    __shared__ ushort Alds[64 * LDSA_STRIDE];
    int tid  = threadIdx.x;
    int wave = tid >> 6;
    int lane = tid & 63;
    int n0 = blockIdx.x * 64;

    // --- A1: stage h rows (coalesced) into Alds[row][128..255] ---
#pragma unroll
    for (int it = 0; it < 4; it++) {
        int chunk = tid + 256 * it;          // 64 rows x 16 chunks
        int row = chunk >> 4;
        int c8  = chunk & 15;
        int node = n0 + row;
        bf16x8 vh = (bf16x8){0,0,0,0,0,0,0,0};
        if (node < N) vh = *(const bf16x8*)(hbf + (size_t)node * D + c8 * 8);
        *(bf16x8*)&Alds[row * LDSA_STRIDE + 128 + c8 * 8] = vh;
    }

    // --- A2: aggregate 64 rows into Alds[row][0..127] ---
    int g  = lane >> 4;          // subgroup 0..3
    int sl = lane & 15;          // 16 lanes x 8 bf16 = 128 elems
    int row0 = wave * 16 + g;    // rows row0 + {0,4,8,12}
    int startp[4], degp[4];
#pragma unroll
    for (int p = 0; p < 4; p++) {
        int node = n0 + row0 + p * 4;
        startp[p] = 0; degp[p] = 0;
        if (node < N) { startp[p] = offs[node]; degp[p] = hist[node]; }
    }
    float acc[4][8];
#pragma unroll
    for (int p = 0; p < 4; p++)
#pragma unroll
        for (int q = 0; q < 8; q++) acc[p][q] = 0.0f;
    int dmax = max(max(degp[0], degp[1]), max(degp[2], degp[3]));
    for (int j = 0; j < dmax; j++) {
#pragma unroll
        for (int p = 0; p < 4; p++) {
            if (j < degp[p]) {
                int s0 = sorted_src[startp[p] + j];
                bf16x8 v = *(const bf16x8*)(hbf + (size_t)s0 * D + sl * 8);
#pragma unroll
                for (int q = 0; q < 8; q++) acc[p][q] += bf2f((ushort)v[q]);
            }
        }
    }
#pragma unroll
    for (int p = 0; p < 4; p++) {
        float inv = 1.0f / fmaxf((float)degp[p], 1.0f);
        bf16x8 o;
#pragma unroll
        for (int q = 0; q < 8; q++) o[q] = (short)f2bf(acc[p][q] * inv);
        *(bf16x8*)&Alds[(row0 + p * 4) * LDSA_STRIDE + sl * 8] = o;
    }
    __syncthreads();

    // --- B: MFMA. B fragments loaded after the barrier (lower peak VGPR). ---
    bf16x8 breg[8][2];
#pragma unroll
    for (int ks = 0; ks < 8; ks++)
#pragma unroll
        for (int jj = 0; jj < 2; jj++) {
            int jb = wave * 2 + jj;
            breg[ks][jj] = *(const bf16x8*)(Bfrag + (size_t)((ks * 8 + jb) * 64 + lane) * 8);
        }

    f32x4 acc2[4][2];
#pragma unroll
    for (int nb = 0; nb < 4; nb++)
#pragma unroll
        for (int jj = 0; jj < 2; jj++)
            acc2[nb][jj] = (f32x4){0.f, 0.f, 0.f, 0.f};

    int arow = lane & 15;
    int akoff = (lane >> 4) * 8;
#pragma unroll
    for (int ks = 0; ks < 8; ks++) {
#pragma unroll
        for (int nb = 0; nb < 4; nb++) {
            bf16x8 a = *(const bf16x8*)&Alds[(nb * 16 + arow) * LDSA_STRIDE + ks * 32 + akoff];
            acc2[nb][0] = __builtin_amdgcn_mfma_f32_16x16x32_bf16(a, breg[ks][0], acc2[nb][0], 0, 0, 0);
            acc2[nb][1] = __builtin_amdgcn_mfma_f32_16x16x32_bf16(a, breg[ks][1], acc2[nb][1], 0, 0, 0);
        }
    }

    float bias0 = bl[wave * 32 + (lane & 15)];
    float bias1 = bl[wave * 32 + 16 + (lane & 15)];
    int rbase = (lane >> 4) * 4;
#pragma unroll
    for (int nb = 0; nb < 4; nb++) {
#pragma unroll
        for (int r = 0; r < 4; r++) {
            int row = nb * 16 + rbase + r;
            if (n0 + row < N) {
                float* orow = out + (size_t)(n0 + row) * D + wave * 32 + (lane & 15);
                orow[0]  = acc2[nb][0][r] + bias0;
                orow[16] = acc2[nb][1][r] + bias1;
            }
        }
    }
}

extern "C" void kernel_launch(void* const* d_in, const int* in_sizes, int n_in,
                              void* d_out, int out_size, void* d_ws, size_t ws_size,
                              hipStream_t stream) {
    const float* x     = (const float*)d_in[0];
    const int*   ei    = (const int*)  d_in[1];
    const float* mask  = (const float*)d_in[2];
    const float* gamma = (const float*)d_in[3];
    const float* beta  = (const float*)d_in[4];
    const float* Wl    = (const float*)d_in[5];
    const float* bl    = (const float*)d_in[6];
    const float* Wr    = (const float*)d_in[7];
    float* out = (float*)d_out;

    int N = in_sizes[0] / D;   // 100000
    int E = in_sizes[1] / 2;   // 600000
    int chunks = (N + SCAN_CHUNK - 1) / SCAN_CHUNK;  // 98

    // ws layout: hbf[N*D] us | Bfrag[32768] us | hist[N] | offs[N]
    //            | cursor[N] | chunk_sums[128] | sorted_src[E]
    ushort* hbf   = (ushort*)d_ws;
    ushort* Bfrag = hbf + (size_t)N * D;
    int* hist   = (int*)(Bfrag + 32768);
    int* offs   = hist + N;
    int* cursor = offs + N;
    int* csums  = cursor + N;
    int* ssrc   = csums + 128;

    int histBlocks = (E + 255) / 256;      // 2344, dispatched first
    int lnBlocks = (N + 7) / 8;            // 12500: 4 waves x 2 nodes per block

    prep_w<<<512, 256, 0, stream>>>(Wl, Wr, Bfrag, hist, N);
    ln_hist<<<histBlocks + lnBlocks, 256, 0, stream>>>(x, mask, gamma, beta, hbf,
                                                       ei, hist, N, E, histBlocks);
    scan1<<<chunks, 256, 0, stream>>>(hist, offs, csums, N);
    scan_fix<<<(N + 255) / 256, 256, 0, stream>>>(offs, csums, cursor, N);
    sort_edges<<<(E + 255) / 256, 256, 0, stream>>>(ei, cursor, ssrc, E);
    agg_gemm<<<(N + 63) / 64, 256, 0, stream>>>(out, hbf, ssrc, offs, hist, Bfrag, bl, N);
}

// Round 2
// 256.866 us; speedup vs baseline: 1.1157x; 1.1157x over previous
//
#include <hip/hip_runtime.h>

#define LN_EPS 1e-5f
#define D 128
#define SCAN_CHUNK 1024
#define LDSA_STRIDE 264   // bf16 units: 256 + 8 pad; row stride 528B (16B-aligned)

typedef __attribute__((ext_vector_type(4))) float f32x4;
typedef __attribute__((ext_vector_type(8))) short bf16x8;

static __device__ __forceinline__ ushort f2bf(float f) {
    union { float f; unsigned u; } a; a.f = f;
    unsigned r = a.u + 0x7FFF + ((a.u >> 16) & 1);   // RNE
    return (ushort)(r >> 16);
}
static __device__ __forceinline__ float bf2f(ushort u) {
    union { unsigned u; float f; } a; a.u = ((unsigned)u) << 16;
    return a.f;
}

// K0: pack B = [Wl^T ; Wr^T] into MFMA B-fragment order; zero hist + scan flags.
__global__ void prep_w(const float* __restrict__ Wl,
                       const float* __restrict__ Wr,
                       ushort* __restrict__ Bfrag,
                       int* __restrict__ hist,
                       int* __restrict__ csums, int N) {
    int t = blockIdx.x * blockDim.x + threadIdx.x;
    if (t < 8 * 8 * 64 * 8) {
        int i    = t & 7;
        int lane = (t >> 3) & 63;
        int jb   = (t >> 9) & 7;
        int ks   = t >> 12;
        int k = ks * 32 + (lane >> 4) * 8 + i;
        int j = jb * 16 + (lane & 15);
        float v = (k < D) ? Wl[j * D + k] : Wr[j * D + (k - D)];
        Bfrag[t] = f2bf(v);
    }
    if (t < 128) csums[t] = 0;
    for (int i = t; i < N; i += gridDim.x * blockDim.x) hist[i] = 0;
}

// K1: dst-degree histogram, 4 edges/thread.
__global__ void hist_k(const int* __restrict__ ei, int* __restrict__ hist, int E) {
    int base = (blockIdx.x * blockDim.x + threadIdx.x) * 4;
    const int* dst = ei + E;
    if (base + 3 < E) {
        int4 d = *(const int4*)(dst + base);
        atomicAdd(&hist[d.x], 1);
        atomicAdd(&hist[d.y], 1);
        atomicAdd(&hist[d.z], 1);
        atomicAdd(&hist[d.w], 1);
    } else {
        for (int i = base; i < E && i < base + 4; i++) atomicAdd(&hist[dst[i]], 1);
    }
}

// K2: single-pass exclusive scan (decoupled aggregate lookup). 98 blocks, all
// co-resident on 256 CUs -> spin on predecessors is safe. Writes offs AND the
// scatter cursor (merges old scan1 + scan_fix, saves a dispatch).
__global__ void scan_all(const int* __restrict__ hist, int* __restrict__ offs,
                         int* __restrict__ cursor, int* __restrict__ csums, int N) {
    __shared__ int lds[256];
    __shared__ int base_s;
    int base = blockIdx.x * SCAN_CHUNK;
    int t = threadIdx.x;
    int idx0 = base + t * 4;
    int v[4];
#pragma unroll
    for (int i = 0; i < 4; i++) {
        int idx = idx0 + i;
        v[i] = (idx < N) ? hist[idx] : 0;
    }
    lds[t] = v[0] + v[1] + v[2] + v[3];
    __syncthreads();
    for (int off = 1; off < 256; off <<= 1) {
        int add = (t >= off) ? lds[t - off] : 0;
        __syncthreads();
        lds[t] += add;
        __syncthreads();
    }
    int run = (t == 0) ? 0 : lds[t - 1];
    if (t == 255)
        __hip_atomic_store(&csums[blockIdx.x], lds[255] | 0x40000000,
                           __ATOMIC_RELEASE, __HIP_MEMORY_SCOPE_AGENT);
    if (t < 64) {
        int b = (int)blockIdx.x;
        int acc = 0;
        for (int c = t; c < b; c += 64) {
            int w;
            do {
                w = __hip_atomic_load(&csums[c], __ATOMIC_ACQUIRE,
                                      __HIP_MEMORY_SCOPE_AGENT);
            } while (!(w & 0x40000000));
            acc += w & 0x3FFFFFFF;
        }
#pragma unroll
        for (int off = 32; off > 0; off >>= 1) acc += __shfl_xor(acc, off);
        if (t == 0) base_s = acc;
    }
    __syncthreads();
    run += base_s;
#pragma unroll
    for (int i = 0; i < 4; i++) {
        int idx = idx0 + i;
        if (idx < N) {
            offs[idx] = run;
            cursor[idx] = run;
        }
        run += v[i];
    }
}

// K3 (merged): blocks [0, lnBlocks): LayerNorm+ReLU+mask -> bf16 h (2 nodes
// per wave, float4 loads). Blocks after: edge scatter (counting-sort place).
// LN first (round-0's working order): streaming blocks fill CUs, scatter
// atomics trickle behind.
__global__ void ln_sort(const float* __restrict__ x,
                        const float* __restrict__ mask,
                        const float* __restrict__ gamma,
                        const float* __restrict__ beta,
                        ushort* __restrict__ hbf,
                        const int* __restrict__ ei,
                        int* __restrict__ cursor,
                        int* __restrict__ sorted_src,
                        int N, int E, int lnBlocks) {
    if ((int)blockIdx.x >= lnBlocks) {
        int e = ((int)blockIdx.x - lnBlocks) * (int)blockDim.x + (int)threadIdx.x;
        if (e < E) {
            int dst = ei[E + e];
            int pos = atomicAdd(&cursor[dst], 1);
            sorted_src[pos] = ei[e];
        }
        return;
    }
    int lane = threadIdx.x & 63;
    int wid  = ((int)blockIdx.x * (int)blockDim.x + (int)threadIdx.x) >> 6;
    int node = wid * 2 + (lane >> 5);
    if (node >= N) return;
    int sl = lane & 31;
    f32x4 v = ((const f32x4*)(x + (size_t)node * D))[sl];
    float s  = v.x + v.y + v.z + v.w;
    float ss = v.x * v.x + v.y * v.y + v.z * v.z + v.w * v.w;
#pragma unroll
    for (int off = 16; off > 0; off >>= 1) {
        s  += __shfl_xor(s, off);
        ss += __shfl_xor(ss, off);
    }
    float mu  = s * (1.0f / D);
    float var = ss * (1.0f / D) - mu * mu;
    float rs  = rsqrtf(var + LN_EPS);
    f32x4 g = ((const f32x4*)gamma)[sl];
    f32x4 b = ((const f32x4*)beta)[sl];
    f32x4 m = ((const f32x4*)(mask + (size_t)node * D))[sl];
    ushort4 o;
    o.x = f2bf(fmaxf((v.x - mu) * rs * g.x + b.x, 0.0f) * m.x);
    o.y = f2bf(fmaxf((v.y - mu) * rs * g.y + b.y, 0.0f) * m.y);
    o.z = f2bf(fmaxf((v.z - mu) * rs * g.z + b.z, 0.0f) * m.z);
    o.w = f2bf(fmaxf((v.w - mu) * rs * g.w + b.w, 0.0f) * m.w);
    ((ushort4*)(hbf + (size_t)node * D))[sl] = o;
}

// K4 (fused agg+GEMM): per 64-node block: stage h into A-tile, mean-aggregate
// into A-tile, MFMA. Gather loop: 8 rows in flight per subgroup (unroll x2),
// index loads pipelined one pair ahead, row loads UNCONDITIONAL with
// last-edge-clamped addresses; validity folded into the accumulate as a 0/1
// FMA scale (same VALU cost as an add, removes exec-masked load
// serialization). __launch_bounds__(256,4): LDS 33.8KB allows 4 blocks/CU.
__global__ void __launch_bounds__(256, 4)
agg_gemm(float* __restrict__ out,
         const ushort* __restrict__ hbf,
         const int* __restrict__ sorted_src,
         const int* __restrict__ offs,
         const int* __restrict__ hist,
         const ushort* __restrict__ Bfrag,
         const float* __restrict__ bl,
         int N, int E) {
    __shared__ ushort Alds[64 * LDSA_STRIDE];
    int tid  = threadIdx.x;
    int wave = tid >> 6;
    int lane = tid & 63;
    int n0 = blockIdx.x * 64;

    // stage h rows (coalesced) into Alds[row][128..255]
#pragma unroll
    for (int it = 0; it < 4; it++) {
        int chunk = tid + 256 * it;
        int row = chunk >> 4;
        int c8  = chunk & 15;
        int node = n0 + row;
        bf16x8 vh = (bf16x8){0,0,0,0,0,0,0,0};
        if (node < N) vh = *(const bf16x8*)(hbf + (size_t)node * D + c8 * 8);
        *(bf16x8*)&Alds[row * LDSA_STRIDE + 128 + c8 * 8] = vh;
    }

    // aggregate 64 rows into Alds[row][0..127]
    int g  = lane >> 4;
    int sl = lane & 15;
    int row0 = wave * 16 + g;           // rows row0 + {0,4,8,12}
    int start[4], deg[4], dm1[4];
#pragma unroll
    for (int p = 0; p < 4; p++) {
        int node = n0 + row0 + p * 4;
        start[p] = 0; deg[p] = 0;
        if (node < N) { start[p] = offs[node]; deg[p] = hist[node]; }
        dm1[p] = deg[p] - 1; if (dm1[p] < 0) dm1[p] = 0;
    }
    float acc[4][8];
#pragma unroll
    for (int p = 0; p < 4; p++)
#pragma unroll
        for (int q = 0; q < 8; q++) acc[p][q] = 0.0f;

    int dmax = max(max(deg[0], deg[1]), max(deg[2], deg[3]));
    int Em = E - 1;
    int ia[4], ib[4];
#pragma unroll
    for (int p = 0; p < 4; p++) {
        int pa = start[p];                         if (pa > Em) pa = Em;
        int j1 = (1 < dm1[p]) ? 1 : dm1[p];
        int pb = start[p] + j1;                    if (pb > Em) pb = Em;
        ia[p] = sorted_src[pa];
        ib[p] = sorted_src[pb];
    }
    for (int j = 0; j < dmax; j += 2) {
        int ca[4], cb[4];
#pragma unroll
        for (int p = 0; p < 4; p++) { ca[p] = ia[p]; cb[p] = ib[p]; }
        // prefetch indices for j+2 / j+3 (clamped to the node's last edge)
#pragma unroll
        for (int p = 0; p < 4; p++) {
            int j2 = (j + 2 < dm1[p]) ? j + 2 : dm1[p];
            int j3 = (j + 3 < dm1[p]) ? j + 3 : dm1[p];
            int pa = start[p] + j2; if (pa > Em) pa = Em;
            int pb = start[p] + j3; if (pb > Em) pb = Em;
            ia[p] = sorted_src[pa];
            ib[p] = sorted_src[pb];
        }
#pragma unroll
        for (int p = 0; p < 4; p++) {
            bf16x8 v = *(const bf16x8*)(hbf + (size_t)ca[p] * D + sl * 8);
            float m = (j < deg[p]) ? 1.0f : 0.0f;
#pragma unroll
            for (int q = 0; q < 8; q++) acc[p][q] += bf2f((ushort)v[q]) * m;
        }
#pragma unroll
        for (int p = 0; p < 4; p++) {
            bf16x8 v = *(const bf16x8*)(hbf + (size_t)cb[p] * D + sl * 8);
            float m = (j + 1 < deg[p]) ? 1.0f : 0.0f;
#pragma unroll
            for (int q = 0; q < 8; q++) acc[p][q] += bf2f((ushort)v[q]) * m;
        }
    }
#pragma unroll
    for (int p = 0; p < 4; p++) {
        float inv = 1.0f / fmaxf((float)deg[p], 1.0f);
        bf16x8 o;
#pragma unroll
        for (int q = 0; q < 8; q++) o[q] = (short)f2bf(acc[p][q] * inv);
        *(bf16x8*)&Alds[(row0 + p * 4) * LDSA_STRIDE + sl * 8] = o;
    }
    __syncthreads();

    // MFMA: [magg | h] @ B + bias
    bf16x8 breg[8][2];
#pragma unroll
    for (int ks = 0; ks < 8; ks++)
#pragma unroll
        for (int jj = 0; jj < 2; jj++) {
            int jb = wave * 2 + jj;
            breg[ks][jj] = *(const bf16x8*)(Bfrag + (size_t)((ks * 8 + jb) * 64 + lane) * 8);
        }

    f32x4 acc2[4][2];
#pragma unroll
    for (int nb = 0; nb < 4; nb++)
#pragma unroll
        for (int jj = 0; jj < 2; jj++)
            acc2[nb][jj] = (f32x4){0.f, 0.f, 0.f, 0.f};

    int arow = lane & 15;
    int akoff = (lane >> 4) * 8;
#pragma unroll
    for (int ks = 0; ks < 8; ks++) {
#pragma unroll
        for (int nb = 0; nb < 4; nb++) {
            bf16x8 a = *(const bf16x8*)&Alds[(nb * 16 + arow) * LDSA_STRIDE + ks * 32 + akoff];
            acc2[nb][0] = __builtin_amdgcn_mfma_f32_16x16x32_bf16(a, breg[ks][0], acc2[nb][0], 0, 0, 0);
            acc2[nb][1] = __builtin_amdgcn_mfma_f32_16x16x32_bf16(a, breg[ks][1], acc2[nb][1], 0, 0, 0);
        }
    }

    float bias0 = bl[wave * 32 + (lane & 15)];
    float bias1 = bl[wave * 32 + 16 + (lane & 15)];
    int rbase = (lane >> 4) * 4;
#pragma unroll
    for (int nb = 0; nb < 4; nb++) {
#pragma unroll
        for (int r = 0; r < 4; r++) {
            int row = nb * 16 + rbase + r;
            if (n0 + row < N) {
                float* orow = out + (size_t)(n0 + row) * D + wave * 32 + (lane & 15);
                orow[0]  = acc2[nb][0][r] + bias0;
                orow[16] = acc2[nb][1][r] + bias1;
            }
        }
    }
}

extern "C" void kernel_launch(void* const* d_in, const int* in_sizes, int n_in,
                              void* d_out, int out_size, void* d_ws, size_t ws_size,
                              hipStream_t stream) {
    const float* x     = (const float*)d_in[0];
    const int*   ei    = (const int*)  d_in[1];
    const float* mask  = (const float*)d_in[2];
    const float* gamma = (const float*)d_in[3];
    const float* beta  = (const float*)d_in[4];
    const float* Wl    = (const float*)d_in[5];
    const float* bl    = (const float*)d_in[6];
    const float* Wr    = (const float*)d_in[7];
    float* out = (float*)d_out;

    int N = in_sizes[0] / D;   // 100000
    int E = in_sizes[1] / 2;   // 600000
    int chunks = (N + SCAN_CHUNK - 1) / SCAN_CHUNK;  // 98

    // ws layout: hbf[N*D] us | Bfrag[32768] us | hist[N] | offs[N]
    //            | cursor[N] | chunk_sums[128] | sorted_src[E]
    ushort* hbf   = (ushort*)d_ws;
    ushort* Bfrag = hbf + (size_t)N * D;
    int* hist   = (int*)(Bfrag + 32768);
    int* offs   = hist + N;
    int* cursor = offs + N;
    int* csums  = cursor + N;
    int* ssrc   = csums + 128;

    int lnBlocks   = (N + 7) / 8;          // 12500 (2 nodes/wave, 4 waves/block)
    int sortBlocks = (E + 255) / 256;      // 2344, dispatched after LN

    prep_w<<<512, 256, 0, stream>>>(Wl, Wr, Bfrag, hist, csums, N);
    hist_k<<<(E / 4 + 255) / 256, 256, 0, stream>>>(ei, hist, E);
    scan_all<<<chunks, 256, 0, stream>>>(hist, offs, cursor, csums, N);
    ln_sort<<<lnBlocks + sortBlocks, 256, 0, stream>>>(x, mask, gamma, beta, hbf,
                                                       ei, cursor, ssrc, N, E, lnBlocks);
    agg_gemm<<<(N + 63) / 64, 256, 0, stream>>>(out, hbf, ssrc, offs, hist, Bfrag,
                                                bl, N, E);
}